// Round 12
// baseline (160.036 us; speedup 1.0000x reference)
//
#include <hip/hip_runtime.h>
#include <hip/hip_bf16.h>

#define B_   32
#define L_   2048
#define CIN  256
#define HID  512
#define TL   32
#define NTILES (B_ * L_ / TL) // 2048
#define TPB  8                // tiles per block (256 rows, never crosses batch)
#define NBLK (NTILES / TPB)   // 256 blocks = 1 per CU

typedef __bf16 bf16_t;
typedef __bf16 bf16x8 __attribute__((ext_vector_type(8)));
typedef __bf16 bf16x4 __attribute__((ext_vector_type(4)));
typedef float  f32x4  __attribute__((ext_vector_type(4)));

// LDS map (128 KB):
//   F32 staging buf @ 0      : 2 pipes x 32 rows x 1024 B = 64 KB (LINEAR)
//   bf16 A dbuf    @ 65536   : buf b @ 65536 + b*32768; pipe*16384 + row*512
#define F32_OFF 0u
#define ABF_OFF 65536u

// direct global->LDS DMA, 16 B per lane; dest = wave-uniform base + lane*16
__device__ __forceinline__ void gload_lds16(const float* g, char* lds) {
    __builtin_amdgcn_global_load_lds(
        (const __attribute__((address_space(1))) void*)g,
        (__attribute__((address_space(3))) void*)lds, 16, 0, 0);
}

// ---------------------------------------------------------------------------
// Kernel 1: compose Wc = W2 @ W1 (fp32 math -> bf16), bc = W2 @ b1 + b2.
// No activation between the two 1x1 convs -> they fuse into one projection.
// ---------------------------------------------------------------------------
__global__ void compose_kernel(const float* __restrict__ W1, const float* __restrict__ W2,
                               const float* __restrict__ b1, const float* __restrict__ b2,
                               bf16_t* __restrict__ Wc, float* __restrict__ bc)
{
    const int g = blockIdx.x;            // 512
    const int c = threadIdx.x;           // 256
    const float* w2row = W2 + (size_t)g * HID;
    float s0 = 0.f, s1 = 0.f, s2 = 0.f, s3 = 0.f;
    for (int h = 0; h < HID; h += 4) {
        s0 = fmaf(w2row[h + 0], W1[(size_t)(h + 0) * CIN + c], s0);
        s1 = fmaf(w2row[h + 1], W1[(size_t)(h + 1) * CIN + c], s1);
        s2 = fmaf(w2row[h + 2], W1[(size_t)(h + 2) * CIN + c], s2);
        s3 = fmaf(w2row[h + 3], W1[(size_t)(h + 3) * CIN + c], s3);
    }
    Wc[(size_t)g * CIN + c] = (bf16_t)((s0 + s1) + (s2 + s3));
    if (c == 0) {
        float t0 = 0.f, t1 = 0.f;
        for (int h = 0; h < HID; h += 2) {
            t0 = fmaf(w2row[h], b1[h], t0);
            t1 = fmaf(w2row[h + 1], b1[h + 1], t1);
        }
        bc[g] = t0 + t1 + b2[g];
    }
}

// ---------------------------------------------------------------------------
// Kernel 2: fused single-GEMM + tanh-pair-product + row-reduction.
// 256 blocks x 1024 thr (16 waves), 8 consecutive 32-row tiles per block.
// Staging is REGISTER-FREE (the R5/R6/R8/R9/R11 spill killer):
//   global_load_lds DMAs the next tile's fp32 rows into a linear LDS buffer
//   (wave wv owns rows {wv, wv+16} of each pipe: 4 x 1 KB DMA calls);
//   after the gemm, each wave waits ITS vmcnt(0) and converts ITS OWN rows
//   fp32->bf16 into the swizzled A double-buffer (transient regs only).
// One __syncthreads per tile. Gemm identical to R11 (0 bank conflicts):
// swapped-operand MFMA, bc folded into acc init, paired tanh into psum.
// ---------------------------------------------------------------------------
__global__ __launch_bounds__(1024, 4)
void fused_kernel(const float* __restrict__ x, const float* __restrict__ y,
                  const bf16_t* __restrict__ Wc, const float* __restrict__ bc,
                  float* __restrict__ partial)
{
    __shared__ char U[131072];           // 128 KB

    const int tid  = threadIdx.x;
    const int lane = tid & 63;
    const int wv   = tid >> 6;           // wave 0..15
    const int l15  = lane & 15;
    const int l4   = lane >> 4;
    const int col0 = wv * 32;

    const size_t row0 = (size_t)(blockIdx.x * TPB) * TL;   // first global row

    // --- DMA one tile's 64 rows: wave wv owns (pipe, row) for c=0..3:
    //     pipe = c>>1, row = (c&1)*16 + wv. Linear LDS, linear global.
    auto stage_dma = [&](int t) {
#pragma unroll
        for (int c = 0; c < 4; ++c) {
            const int pipe = c >> 1;
            const int row  = ((c & 1) << 4) + wv;
            const float* src = (pipe ? y : x) + (row0 + (size_t)t * TL + row) * CIN + lane * 4;
            char* dst = U + F32_OFF + (unsigned)(pipe * 32768 + row * 1024);
            gload_lds16(src, dst);
        }
    };
    // --- convert this wave's 4 rows fp32 -> bf16 (swizzled) into buf
    auto cvt_rows = [&](int buf) {
#pragma unroll
        for (int c = 0; c < 4; ++c) {
            const int pipe = c >> 1;
            const int row  = ((c & 1) << 4) + wv;
            f32x4 v = *reinterpret_cast<const f32x4*>(
                U + F32_OFF + (unsigned)(pipe * 32768 + row * 1024 + lane * 16));
            bf16x4 h;
            h[0] = (bf16_t)v[0]; h[1] = (bf16_t)v[1];
            h[2] = (bf16_t)v[2]; h[3] = (bf16_t)v[3];
            *reinterpret_cast<bf16x4*>(
                U + ABF_OFF + (unsigned)(buf * 32768 + pipe * 16384 + row * 512) +
                (((unsigned)(lane * 8)) ^ ((unsigned)((row & 15) << 4)))) = h;
        }
    };

    // bias fragments (bc, fp32) — folded into acc init each tile
    f32x4 bcv[2];
#pragma unroll
    for (int cj = 0; cj < 2; ++cj) {
        float4 t4 = *reinterpret_cast<const float4*>(bc + col0 + cj * 16 + l4 * 4);
        bcv[cj] = (f32x4){t4.x, t4.y, t4.z, t4.w};
    }

    // fragment LDS offsets (R11-proven, 0 conflicts): row r = ri*16+l15,
    // byte = (kk*64 + l4*16) ^ ((r&15)<<4); per-kk addr = base ^ (kk<<6)
    unsigned fbase[2];
#pragma unroll
    for (int ri = 0; ri < 2; ++ri) {
        const int r = ri * 16 + l15;
        fbase[ri] = (unsigned)(r * 512) + (((unsigned)(l4 * 16)) ^ ((unsigned)((r & 15) << 4)));
    }

    f32x4 psum[2];
    psum[0] = (f32x4){0.f, 0.f, 0.f, 0.f};
    psum[1] = (f32x4){0.f, 0.f, 0.f, 0.f};

    // ---- prologue: DMA tile 0, wave-local drain, cvt into buf 0
    stage_dma(0);
    asm volatile("s_waitcnt vmcnt(0)" ::: "memory");
    cvt_rows(0);
    __syncthreads();

    int cur = 0;
    for (int t = 0; t < TPB; ++t) {
        if (t + 1 < TPB) stage_dma(t + 1);     // DMA flies under the gemm

        f32x4 accx[2][2], accy[2][2];
#pragma unroll
        for (int ri = 0; ri < 2; ++ri)
#pragma unroll
            for (int cj = 0; cj < 2; ++cj) { accx[ri][cj] = bcv[cj]; accy[ri][cj] = bcv[cj]; }

        const unsigned abuf = ABF_OFF + (unsigned)(cur * 32768);
        for (int kk = 0; kk < CIN / 32; ++kk) {
            bf16x8 w[2];
#pragma unroll
            for (int cj = 0; cj < 2; ++cj)
                w[cj] = *reinterpret_cast<const bf16x8*>(
                    Wc + (size_t)(col0 + cj * 16 + l15) * CIN + kk * 32 + l4 * 8);
            __builtin_amdgcn_s_setprio(1);
#pragma unroll
            for (int ri = 0; ri < 2; ++ri) {
                const unsigned o = abuf + (fbase[ri] ^ (unsigned)(kk << 6));
                bf16x8 ax = *reinterpret_cast<const bf16x8*>(U + o);
                bf16x8 ay = *reinterpret_cast<const bf16x8*>(U + 16384u + o);
#pragma unroll
                for (int cj = 0; cj < 2; ++cj) {
                    accx[ri][cj] = __builtin_amdgcn_mfma_f32_16x16x32_bf16(w[cj], ax, accx[ri][cj], 0, 0, 0);
                    accy[ri][cj] = __builtin_amdgcn_mfma_f32_16x16x32_bf16(w[cj], ay, accy[ri][cj], 0, 0, 0);
                }
            }
            __builtin_amdgcn_s_setprio(0);
        }

        // paired tanh product -> psum.
        // tanh(a)tanh(b) = (Ea-1)(Eb-1)/((Ea+1)(Eb+1)), E = e^{2v} clamped.
#pragma unroll
        for (int ri = 0; ri < 2; ++ri)
#pragma unroll
            for (int cj = 0; cj < 2; ++cj)
#pragma unroll
                for (int r2 = 0; r2 < 4; ++r2) {
                    float a = fminf(fmaxf(accx[ri][cj][r2], -9.0f), 9.0f);
                    float c = fminf(fmaxf(accy[ri][cj][r2], -9.0f), 9.0f);
                    float Ea = exp2f(a * 2.885390081777927f);
                    float Eb = exp2f(c * 2.885390081777927f);
                    float num = (Ea - 1.0f) * (Eb - 1.0f);
                    float den = (Ea + 1.0f) * (Eb + 1.0f);
                    psum[cj][r2] += num * __builtin_amdgcn_rcpf(den);
                }

        if (t + 1 < TPB) {
            // wave-local: wait ONLY this wave's DMA, then convert its rows
            asm volatile("s_waitcnt vmcnt(0)" ::: "memory");
            cvt_rows(cur ^ 1);
        }
        __syncthreads();               // publish bf16[cur^1]; fence F32 reuse
        cur ^= 1;
    }

    // reduce the 16 row-lanes (l15 bits; l4 indexes the output g-chunk)
#pragma unroll
    for (int cj = 0; cj < 2; ++cj)
#pragma unroll
        for (int r2 = 0; r2 < 4; ++r2) {
            float s = psum[cj][r2];
            s += __shfl_xor(s, 1);
            s += __shfl_xor(s, 2);
            s += __shfl_xor(s, 4);
            s += __shfl_xor(s, 8);
            psum[cj][r2] = s;
        }
    if (l15 == 0) {
#pragma unroll
        for (int cj = 0; cj < 2; ++cj) {
            float4 o4 = make_float4(psum[cj][0], psum[cj][1], psum[cj][2], psum[cj][3]);
            *reinterpret_cast<float4*>(partial + (size_t)blockIdx.x * HID + col0 + cj * 16 + l4 * 4) = o4;
        }
    }
}

// ---------------------------------------------------------------------------
// Kernel 3: sum the 8 block-partials per batch -> out[B][HID]
// ---------------------------------------------------------------------------
__global__ void reduce_kernel(const float* __restrict__ partial, float* __restrict__ out)
{
    int b = blockIdx.x;                  // 32
    int g = threadIdx.x;                 // 512
    float s = 0.f;
#pragma unroll
    for (int k = 0; k < TPB; ++k)
        s += partial[((size_t)(b * TPB + k)) * HID + g];
    out[b * HID + g] = s;
}

extern "C" void kernel_launch(void* const* d_in, const int* in_sizes, int n_in,
                              void* d_out, int out_size, void* d_ws, size_t ws_size,
                              hipStream_t stream)
{
    const float* x  = (const float*)d_in[0];
    const float* y  = (const float*)d_in[1];
    const float* W1 = (const float*)d_in[2];
    const float* b1 = (const float*)d_in[3];
    const float* W2 = (const float*)d_in[4];
    const float* b2 = (const float*)d_in[5];
    float* out = (float*)d_out;

    char* ws = (char*)d_ws;
    bf16_t* Wc     = (bf16_t*)ws;                    // 256 KB
    float*  bc     = (float*)(ws + (256 << 10));     // 2 KB
    float*  partial = (float*)(ws + (264 << 10));    // 512 KB (256 blocks x 512)

    hipLaunchKernelGGL(compose_kernel, dim3(HID), dim3(CIN), 0, stream, W1, W2, b1, b2, Wc, bc);
    hipLaunchKernelGGL(fused_kernel, dim3(NBLK), dim3(1024), 0, stream, x, y, Wc, bc, partial);
    hipLaunchKernelGGL(reduce_kernel, dim3(B_), dim3(512), 0, stream, partial, out);
}

// Round 13
// 139.637 us; speedup vs baseline: 1.1461x; 1.1461x over previous
//
#include <hip/hip_runtime.h>
#include <hip/hip_bf16.h>

#define B_   32
#define L_   2048
#define CIN  256
#define HID  512
#define TL   32
#define TPB  8                     // tiles per block-group (256 rows)
#define NGRP (B_ * L_ / TL / TPB)  // 256 row-groups
#define NBLK (NGRP * 2)            // x2 G-halves = 512 blocks (2 per CU)

typedef __bf16 bf16_t;
typedef __bf16 bf16x8 __attribute__((ext_vector_type(8)));
typedef __bf16 bf16x4 __attribute__((ext_vector_type(4)));
typedef float  f32x4  __attribute__((ext_vector_type(4)));

// ---------------------------------------------------------------------------
// Kernel 1: compose Wc = W2 @ W1 (fp32 math -> bf16), bc = W2 @ b1 + b2.
// No activation between the two 1x1 convs -> they fuse into one projection.
// ---------------------------------------------------------------------------
__global__ void compose_kernel(const float* __restrict__ W1, const float* __restrict__ W2,
                               const float* __restrict__ b1, const float* __restrict__ b2,
                               bf16_t* __restrict__ Wc, float* __restrict__ bc)
{
    const int g = blockIdx.x;            // 512
    const int c = threadIdx.x;           // 256
    const float* w2row = W2 + (size_t)g * HID;
    float s0 = 0.f, s1 = 0.f, s2 = 0.f, s3 = 0.f;
    for (int h = 0; h < HID; h += 4) {
        s0 = fmaf(w2row[h + 0], W1[(size_t)(h + 0) * CIN + c], s0);
        s1 = fmaf(w2row[h + 1], W1[(size_t)(h + 1) * CIN + c], s1);
        s2 = fmaf(w2row[h + 2], W1[(size_t)(h + 2) * CIN + c], s2);
        s3 = fmaf(w2row[h + 3], W1[(size_t)(h + 3) * CIN + c], s3);
    }
    Wc[(size_t)g * CIN + c] = (bf16_t)((s0 + s1) + (s2 + s3));
    if (c == 0) {
        float t0 = 0.f, t1 = 0.f;
        for (int h = 0; h < HID; h += 2) {
            t0 = fmaf(w2row[h], b1[h], t0);
            t1 = fmaf(w2row[h + 1], b1[h + 1], t1);
        }
        bc[g] = t0 + t1 + b2[g];
    }
}

// ---------------------------------------------------------------------------
// Kernel 2: fused single-GEMM + tanh-pair-product + row-reduction.
// 512 blocks x 512 thr (8 waves). Block (grp, half): 8 consecutive 32-row
// tiles x 256 output channels (half of HID). Wave w owns cols
// gc0 = half*256 + w*32 .. +32 (cj=0,1), rows 0..31 (ri=0,1 x l15), both
// pipes -> acc = 32 AGPR.
// THE FIX for the R5/R6/R8/R9/R11/R12 spill: 512-thr block + launch_bounds
// (512,4) -> 128 total regs, arch cap = 128-32 = 96; arch ledger ~74
// (psum 8 + bcv 8 + v[4] 16 + w 8 + frags 16 + addr/consts ~18). 22 free.
// LDS = bf16 A-dbuf only (2 x 32 KB) -> 2 blocks/CU (16 waves): the
// co-resident block's gemm covers this block's stage latency.
// Staging split: load h0 at tile top, swrite h0 + load h1 mid-gemm,
// swrite h1 after tanh; one barrier per tile. Adjacent blockIdx pair =
// same rows, other half -> x/y L2-shared (HBM reads them once).
// ---------------------------------------------------------------------------
__global__ __launch_bounds__(512, 4)
void fused_kernel(const float* __restrict__ x, const float* __restrict__ y,
                  const bf16_t* __restrict__ Wc, const float* __restrict__ bc,
                  float* __restrict__ partial)
{
    __shared__ char U[65536];            // 2 bufs x (2 pipes x 32 rows x 512 B)

    const int tid  = threadIdx.x;
    const int lane = tid & 63;
    const int wv   = tid >> 6;           // wave 0..7
    const int l15  = lane & 15;
    const int l4   = lane >> 4;
    const int grp  = blockIdx.x >> 1;
    const int half = blockIdx.x & 1;
    const int gc0  = half * 256 + wv * 32;   // this wave's output-col base

    // staging identity: threads 0-255 stage x, 256-511 stage y; 8 thr/row
    const int sp = tid >> 8;
    const int sr = (tid & 255) >> 3;     // row 0..31
    const int sq = tid & 7;              // float4 slot
    const unsigned sswz = (unsigned)((sr & 15) << 4);
    const unsigned soff = (unsigned)(sp * 16384 + sr * 512);

    const float* sptr = (sp ? y : x) + ((size_t)grp * (TPB * TL) + sr) * CIN;

    float4 v[4];
    auto sload = [&](const float* rowbase, int h) {
        const float4* s4 = reinterpret_cast<const float4*>(rowbase);
#pragma unroll
        for (int c = 0; c < 4; ++c) v[c] = s4[sq + 8 * (h * 4 + c)];
    };
    auto swrite = [&](int buf, int h) {
        char* p = U + (unsigned)(buf * 32768) + soff;
#pragma unroll
        for (int c = 0; c < 4; ++c) {
            const int f = sq + 8 * (h * 4 + c);
            bf16x4 hh;
            hh[0] = (bf16_t)v[c].x; hh[1] = (bf16_t)v[c].y;
            hh[2] = (bf16_t)v[c].z; hh[3] = (bf16_t)v[c].w;
            *reinterpret_cast<bf16x4*>(p + (((unsigned)(8 * f)) ^ sswz)) = hh;
        }
    };

    // composed-bias fragments, folded into acc init each tile
    f32x4 bcv[2];
#pragma unroll
    for (int cj = 0; cj < 2; ++cj) {
        float4 t4 = *reinterpret_cast<const float4*>(bc + gc0 + cj * 16 + l4 * 4);
        bcv[cj] = (f32x4){t4.x, t4.y, t4.z, t4.w};
    }

    // fragment LDS offsets (R11-proven, 0 conflicts): row r = ri*16+l15,
    // byte = (kk*64 + l4*16) ^ ((r&15)<<4); per-kk addr = base ^ (kk<<6)
    unsigned fbase[2];
#pragma unroll
    for (int ri = 0; ri < 2; ++ri) {
        const int r = ri * 16 + l15;
        fbase[ri] = (unsigned)(r * 512) + (((unsigned)(l4 * 16)) ^ ((unsigned)((r & 15) << 4)));
    }

    f32x4 psum[2];
    psum[0] = (f32x4){0.f, 0.f, 0.f, 0.f};
    psum[1] = (f32x4){0.f, 0.f, 0.f, 0.f};

    // prologue: stage tile 0 into buf 0
    sload(sptr, 0); swrite(0, 0);
    sload(sptr, 1); swrite(0, 1);
    __syncthreads();

    int cur = 0;
    for (int t = 0; t < TPB; ++t) {
        const bool pf = (t + 1 < TPB);
        const float* nptr = sptr + TL * CIN;
        if (pf) sload(nptr, 0);          // issue h0 early (T14)

        f32x4 accx[2][2], accy[2][2];
#pragma unroll
        for (int ri = 0; ri < 2; ++ri)
#pragma unroll
            for (int cj = 0; cj < 2; ++cj) { accx[ri][cj] = bcv[cj]; accy[ri][cj] = bcv[cj]; }

        const unsigned abuf = (unsigned)(cur * 32768);
        auto gemm_k = [&](int k0, int k1) {
            for (int kk = k0; kk < k1; ++kk) {
                bf16x8 w[2];
#pragma unroll
                for (int cj = 0; cj < 2; ++cj)
                    w[cj] = *reinterpret_cast<const bf16x8*>(
                        Wc + (size_t)(gc0 + cj * 16 + l15) * CIN + kk * 32 + l4 * 8);
                __builtin_amdgcn_s_setprio(1);
#pragma unroll
                for (int ri = 0; ri < 2; ++ri) {
                    const unsigned o = abuf + (fbase[ri] ^ (unsigned)(kk << 6));
                    bf16x8 ax = *reinterpret_cast<const bf16x8*>(U + o);
                    bf16x8 ay = *reinterpret_cast<const bf16x8*>(U + 16384u + o);
#pragma unroll
                    for (int cj = 0; cj < 2; ++cj) {
                        accx[ri][cj] = __builtin_amdgcn_mfma_f32_16x16x32_bf16(w[cj], ax, accx[ri][cj], 0, 0, 0);
                        accy[ri][cj] = __builtin_amdgcn_mfma_f32_16x16x32_bf16(w[cj], ay, accy[ri][cj], 0, 0, 0);
                    }
                }
                __builtin_amdgcn_s_setprio(0);
            }
        };

        gemm_k(0, 4);
        if (pf) { swrite(cur ^ 1, 0); sload(nptr, 1); }   // h0 done, issue h1
        gemm_k(4, 8);

        // paired tanh product -> psum.
        // tanh(a)tanh(b) = (Ea-1)(Eb-1)/((Ea+1)(Eb+1)), E = e^{2v} clamped.
#pragma unroll
        for (int ri = 0; ri < 2; ++ri)
#pragma unroll
            for (int cj = 0; cj < 2; ++cj)
#pragma unroll
                for (int r2 = 0; r2 < 4; ++r2) {
                    float a = fminf(fmaxf(accx[ri][cj][r2], -9.0f), 9.0f);
                    float c = fminf(fmaxf(accy[ri][cj][r2], -9.0f), 9.0f);
                    float Ea = exp2f(a * 2.885390081777927f);
                    float Eb = exp2f(c * 2.885390081777927f);
                    float num = (Ea - 1.0f) * (Eb - 1.0f);
                    float den = (Ea + 1.0f) * (Eb + 1.0f);
                    psum[cj][r2] += num * __builtin_amdgcn_rcpf(den);
                }

        if (pf) swrite(cur ^ 1, 1);      // write-late into the idle buffer
        __syncthreads();                 // publish buf[cur^1]
        sptr = nptr;
        cur ^= 1;
    }

    // reduce the 16 row-lanes (l15 bits; l4 indexes the output g-chunk)
#pragma unroll
    for (int cj = 0; cj < 2; ++cj)
#pragma unroll
        for (int r2 = 0; r2 < 4; ++r2) {
            float s = psum[cj][r2];
            s += __shfl_xor(s, 1);
            s += __shfl_xor(s, 2);
            s += __shfl_xor(s, 4);
            s += __shfl_xor(s, 8);
            psum[cj][r2] = s;
        }
    if (l15 == 0) {
#pragma unroll
        for (int cj = 0; cj < 2; ++cj) {
            float4 o4 = make_float4(psum[cj][0], psum[cj][1], psum[cj][2], psum[cj][3]);
            *reinterpret_cast<float4*>(partial + (size_t)grp * HID + gc0 + cj * 16 + l4 * 4) = o4;
        }
    }
}

// ---------------------------------------------------------------------------
// Kernel 3: sum the 8 row-group partials per batch -> out[B][HID]
// (batch = 2048 rows = 8 groups of 256)
// ---------------------------------------------------------------------------
__global__ void reduce_kernel(const float* __restrict__ partial, float* __restrict__ out)
{
    int b = blockIdx.x;                  // 32
    int g = threadIdx.x;                 // 512
    float s = 0.f;
#pragma unroll
    for (int k = 0; k < 8; ++k)
        s += partial[((size_t)(b * 8 + k)) * HID + g];
    out[b * HID + g] = s;
}

extern "C" void kernel_launch(void* const* d_in, const int* in_sizes, int n_in,
                              void* d_out, int out_size, void* d_ws, size_t ws_size,
                              hipStream_t stream)
{
    const float* x  = (const float*)d_in[0];
    const float* y  = (const float*)d_in[1];
    const float* W1 = (const float*)d_in[2];
    const float* b1 = (const float*)d_in[3];
    const float* W2 = (const float*)d_in[4];
    const float* b2 = (const float*)d_in[5];
    float* out = (float*)d_out;

    char* ws = (char*)d_ws;
    bf16_t* Wc     = (bf16_t*)ws;                    // 256 KB
    float*  bc     = (float*)(ws + (256 << 10));     // 2 KB
    float*  partial = (float*)(ws + (264 << 10));    // 512 KB (256 grps x 512)

    hipLaunchKernelGGL(compose_kernel, dim3(HID), dim3(CIN), 0, stream, W1, W2, b1, b2, Wc, bc);
    hipLaunchKernelGGL(fused_kernel, dim3(NBLK), dim3(512), 0, stream, x, y, Wc, bc, partial);
    hipLaunchKernelGGL(reduce_kernel, dim3(B_), dim3(512), 0, stream, partial, out);
}